// Round 2
// baseline (3672.557 us; speedup 1.0000x reference)
//
#include <hip/hip_runtime.h>
#include <math.h>

// Problem constants
#define NBATCH 128
#define NTIME  256
#define NCH    512      // nC (feature channels)
#define NH     512      // hidden size
#define NSTEPS 32
#define NOUT   96       // num_classes - 1
#define MTOT   32768    // NBATCH*NTIME

__device__ __forceinline__ float fast_tanh(float x) {
    x = fminf(fmaxf(x, -30.f), 30.f);
    float u = __expf(2.f * x);
    return (u - 1.f) / (u + 1.f);
}
__device__ __forceinline__ float fast_sigmoid(float x) {
    x = fminf(fmaxf(x, -30.f), 30.f);
    return 1.f / (1.f + __expf(-x));
}
__device__ __forceinline__ float wave_reduce_sum(float s) {
    #pragma unroll
    for (int off = 32; off; off >>= 1) s += __shfl_xor(s, off, 64);
    return s;
}
__device__ __forceinline__ float wave_reduce_max(float s) {
    #pragma unroll
    for (int off = 32; off; off >>= 1) s = fmaxf(s, __shfl_xor(s, off, 64));
    return s;
}

// ---------------------------------------------------------------------------
// feats_proj[m][h] = sum_k feats[k*32768 + m] * Wi2h[h*512 + k]
// (unchanged from round 1)
__global__ __launch_bounds__(256) void k_fp_gemm(const float* __restrict__ feats,
                                                 const float* __restrict__ Wi2h,
                                                 float* __restrict__ fp) {
    __shared__ float As[16][128];
    __shared__ float Bs[16][132];
    const int m0 = (blockIdx.x & 255) * 128;
    const int n0 = (blockIdx.x >> 8) * 128;
    const int tid = threadIdx.x;
    const int tx = tid & 15, ty = tid >> 4;
    float acc[8][8] = {};
    for (int k0 = 0; k0 < NCH; k0 += 16) {
        #pragma unroll
        for (int i = 0; i < 2; ++i) {
            int f4 = tid + i * 256;
            int kk = f4 >> 5, mm4 = (f4 & 31) << 2;
            *(float4*)(&As[kk][mm4]) =
                *(const float4*)(feats + (size_t)(k0 + kk) * MTOT + m0 + mm4);
        }
        #pragma unroll
        for (int i = 0; i < 2; ++i) {
            int f4 = tid + i * 256;
            int nn = f4 >> 2, kq = (f4 & 3) << 2;
            float4 v = *(const float4*)(Wi2h + (size_t)(n0 + nn) * NCH + k0 + kq);
            Bs[kq + 0][nn] = v.x; Bs[kq + 1][nn] = v.y;
            Bs[kq + 2][nn] = v.z; Bs[kq + 3][nn] = v.w;
        }
        __syncthreads();
        #pragma unroll
        for (int kk = 0; kk < 16; ++kk) {
            float a[8], b[8];
            *(float4*)(a)     = *(const float4*)(&As[kk][ty * 8]);
            *(float4*)(a + 4) = *(const float4*)(&As[kk][ty * 8 + 4]);
            *(float4*)(b)     = *(const float4*)(&Bs[kk][tx * 8]);
            *(float4*)(b + 4) = *(const float4*)(&Bs[kk][tx * 8 + 4]);
            #pragma unroll
            for (int i = 0; i < 8; ++i)
                #pragma unroll
                for (int j = 0; j < 8; ++j) acc[i][j] += a[i] * b[j];
        }
        __syncthreads();
    }
    #pragma unroll
    for (int i = 0; i < 8; ++i) {
        float* dst = fp + (size_t)(m0 + ty * 8 + i) * NH + n0 + tx * 8;
        *(float4*)(dst)     = *(float4*)(&acc[i][0]);
        *(float4*)(dst + 4) = *(float4*)(&acc[i][4]);
    }
}

// ---------------------------------------------------------------------------
// Fused attention step for one batch row b (block): hp -> e -> softmax -> ctx.
// 1024 threads = 16 waves.
__global__ __launch_bounds__(1024) void k_att(const float* __restrict__ fp,
                                              const float* __restrict__ feats,
                                              const float* __restrict__ h,
                                              const float* __restrict__ Wh2h,
                                              const float* __restrict__ bh2h,
                                              const float* __restrict__ wscore,
                                              float* __restrict__ ctx) {
    const int b = blockIdx.x;
    const int tid = threadIdx.x;
    const int lane = tid & 63, w = tid >> 6;
    __shared__ float h_s[512];
    __shared__ float hp_s[512];
    __shared__ float e_s[256];
    __shared__ float red[16];

    if (tid < 512) h_s[tid] = h[(size_t)b * NH + tid];
    __syncthreads();

    // Phase 1: hp[j] = h . Wh2h[j,:] + bh2h[j]; wave w covers j = w*32..+31
    {
        float4 ha = *(const float4*)&h_s[lane * 8];
        float4 hb = *(const float4*)&h_s[lane * 8 + 4];
        #pragma unroll 4
        for (int jj = 0; jj < 32; ++jj) {
            int j = w * 32 + jj;
            const float4* wr = (const float4*)(Wh2h + (size_t)j * NH + lane * 8);
            float4 w0 = wr[0], w1 = wr[1];
            float s = ha.x * w0.x + ha.y * w0.y + ha.z * w0.z + ha.w * w0.w +
                      hb.x * w1.x + hb.y * w1.y + hb.z * w1.z + hb.w * w1.w;
            s = wave_reduce_sum(s);
            if (lane == 0) hp_s[j] = s + bh2h[j];
        }
    }
    __syncthreads();

    // Phase 2: e[t] = sum_h tanh(fp[b][t][h] + hp[h]) * wscore[h]; wave w: t = w*16..+15
    {
        float4 hp0 = *(const float4*)&hp_s[lane * 8];
        float4 hp1 = *(const float4*)&hp_s[lane * 8 + 4];
        float4 w0 = *(const float4*)(wscore + lane * 8);
        float4 w1 = *(const float4*)(wscore + lane * 8 + 4);
        #pragma unroll 4
        for (int ti = 0; ti < 16; ++ti) {
            int t = w * 16 + ti;
            const float4* p = (const float4*)(fp + (size_t)(b * NTIME + t) * NH + lane * 8);
            float4 v0 = p[0], v1 = p[1];
            float s = fast_tanh(v0.x + hp0.x) * w0.x + fast_tanh(v0.y + hp0.y) * w0.y +
                      fast_tanh(v0.z + hp0.z) * w0.z + fast_tanh(v0.w + hp0.w) * w0.w +
                      fast_tanh(v1.x + hp1.x) * w1.x + fast_tanh(v1.y + hp1.y) * w1.y +
                      fast_tanh(v1.z + hp1.z) * w1.z + fast_tanh(v1.w + hp1.w) * w1.w;
            s = wave_reduce_sum(s);
            if (lane == 0) e_s[t] = s;
        }
    }
    __syncthreads();

    // Phase 3: softmax over e_s[0..255], alpha written back into e_s
    {
        float v = (tid < 256) ? e_s[tid] : -3.4e38f;
        float m = wave_reduce_max(v);
        if (lane == 0) red[w] = m;
        __syncthreads();
        m = red[0];
        #pragma unroll
        for (int i = 1; i < 16; ++i) m = fmaxf(m, red[i]);
        float ex = (tid < 256) ? __expf(v - m) : 0.f;
        float s = wave_reduce_sum(ex);
        __syncthreads();               // everyone done reading red (max)
        if (lane == 0) red[w] = s;
        __syncthreads();
        s = 0.f;
        #pragma unroll
        for (int i = 0; i < 16; ++i) s += red[i];
        if (tid < 256) e_s[tid] = ex / s;
    }
    __syncthreads();

    // Phase 4: ctx[c] = sum_t feats[c][b][t] * alpha[t]; wave w: c = w*32..+31
    {
        float4 al = *(const float4*)&e_s[lane * 4];
        #pragma unroll 4
        for (int cc = 0; cc < 32; ++cc) {
            int c = w * 32 + cc;
            float4 f = *(const float4*)(feats + (size_t)(c * NBATCH + b) * NTIME + lane * 4);
            float s = f.x * al.x + f.y * al.y + f.z * al.z + f.w * al.w;
            s = wave_reduce_sum(s);
            if (lane == 0) ctx[(size_t)b * NCH + c] = s;
        }
    }
}

// ---------------------------------------------------------------------------
// Fused GRU: computes all six gate dot-products and the combine.
// Output tile: 64 m x 8 n per block; grid 128 = (2 m-tiles) x (64 n-tiles).
// 256 threads: tx = n (8), ty = m-pair (32).
__global__ __launch_bounds__(256) void k_gru(const float* __restrict__ ctx,
                                             const float* __restrict__ hprev,
                                             const float* __restrict__ Wih,
                                             const float* __restrict__ Whh,
                                             const float* __restrict__ bih,
                                             const float* __restrict__ bhh,
                                             float* __restrict__ hnew) {
    __shared__ float Ac[32][66];
    __shared__ float Ah[32][66];
    __shared__ float Bs[6][32][9];
    const int n0 = (blockIdx.x & 63) * 8;
    const int m0 = (blockIdx.x >> 6) * 64;
    const int tid = threadIdx.x;
    const int tx = tid & 7, ty = tid >> 3;
    float acc[2][6] = {};
    for (int k0 = 0; k0 < NH; k0 += 32) {
        #pragma unroll
        for (int i = 0; i < 2; ++i) {
            int f = tid + i * 256;                 // 512 float4: 64 rows x 8
            int mm = f >> 3, kq = (f & 7) << 2;
            float4 vc = *(const float4*)(ctx + (size_t)(m0 + mm) * NH + k0 + kq);
            float4 vh = *(const float4*)(hprev + (size_t)(m0 + mm) * NH + k0 + kq);
            Ac[kq + 0][mm] = vc.x; Ac[kq + 1][mm] = vc.y;
            Ac[kq + 2][mm] = vc.z; Ac[kq + 3][mm] = vc.w;
            Ah[kq + 0][mm] = vh.x; Ah[kq + 1][mm] = vh.y;
            Ah[kq + 2][mm] = vh.z; Ah[kq + 3][mm] = vh.w;
        }
        for (int f = tid; f < 384; f += 256) {     // 6 gates x 8 n x 8 f4
            int g = f >> 6, r = f & 63;
            int nn = r >> 3, kq = (r & 7) << 2;
            const float* W = (g < 3) ? Wih : Whh;
            int row = (g % 3) * NH + n0 + nn;
            float4 v = *(const float4*)(W + (size_t)row * NH + k0 + kq);
            Bs[g][kq + 0][nn] = v.x; Bs[g][kq + 1][nn] = v.y;
            Bs[g][kq + 2][nn] = v.z; Bs[g][kq + 3][nn] = v.w;
        }
        __syncthreads();
        #pragma unroll
        for (int k = 0; k < 32; ++k) {
            float ac0 = Ac[k][ty * 2], ac1 = Ac[k][ty * 2 + 1];
            float ah0 = Ah[k][ty * 2], ah1 = Ah[k][ty * 2 + 1];
            float bw[6];
            #pragma unroll
            for (int g = 0; g < 6; ++g) bw[g] = Bs[g][k][tx];
            #pragma unroll
            for (int g = 0; g < 3; ++g) {
                acc[0][g] += ac0 * bw[g];
                acc[1][g] += ac1 * bw[g];
            }
            #pragma unroll
            for (int g = 3; g < 6; ++g) {
                acc[0][g] += ah0 * bw[g];
                acc[1][g] += ah1 * bw[g];
            }
        }
        __syncthreads();
    }
    const int n = n0 + tx;
    float bir = bih[n], biz = bih[n + NH], bin = bih[n + 2 * NH];
    float bhr = bhh[n], bhz = bhh[n + NH], bhn = bhh[n + 2 * NH];
    #pragma unroll
    for (int i = 0; i < 2; ++i) {
        int m = m0 + ty * 2 + i;
        float ir = acc[i][0] + bir, iz = acc[i][1] + biz, in_ = acc[i][2] + bin;
        float hr = acc[i][3] + bhr, hz = acc[i][4] + bhz, hn = acc[i][5] + bhn;
        float r = fast_sigmoid(ir + hr);
        float z = fast_sigmoid(iz + hz);
        float ng = fast_tanh(in_ + r * hn);
        float hv = hprev[(size_t)m * NH + n];
        hnew[(size_t)m * NH + n] = (1.f - z) * ng + z * hv;
    }
}

// ---------------------------------------------------------------------------
// probs = hid(flattened per-batch) @ Wgen^T + bgen (unchanged from round 1)
__global__ __launch_bounds__(256) void k_gen(const float* __restrict__ hid,
                                             const float* __restrict__ Wgen,
                                             const float* __restrict__ bgen,
                                             float* __restrict__ out) {
    __shared__ float As[32][36];
    __shared__ float Bs[32][97];
    const int m0 = blockIdx.x * 32;
    const int tid = threadIdx.x;
    const int tx = tid & 31, ty = tid >> 5;
    float acc[4][3] = {};
    for (int k0 = 0; k0 < 512; k0 += 32) {
        {
            int mm = tid >> 3, kq = (tid & 7) << 2;
            int m = m0 + mm, s = m & 31, b = m >> 5;
            float4 v = *(const float4*)(hid + (size_t)(s + 1) * 65536 + b * 512 + k0 + kq);
            *(float4*)(&As[mm][kq]) = v;
        }
        #pragma unroll
        for (int i = 0; i < 3; ++i) {
            int f4 = tid + i * 256;
            int nn = f4 >> 3, kq = (f4 & 7) << 2;
            float4 v = *(const float4*)(Wgen + (size_t)nn * 512 + k0 + kq);
            Bs[kq + 0][nn] = v.x; Bs[kq + 1][nn] = v.y;
            Bs[kq + 2][nn] = v.z; Bs[kq + 3][nn] = v.w;
        }
        __syncthreads();
        #pragma unroll
        for (int kk = 0; kk < 32; ++kk) {
            float bv[3];
            #pragma unroll
            for (int j = 0; j < 3; ++j) bv[j] = Bs[kk][tx * 3 + j];
            #pragma unroll
            for (int i = 0; i < 4; ++i) {
                float a = As[ty * 4 + i][kk];
                #pragma unroll
                for (int j = 0; j < 3; ++j) acc[i][j] += a * bv[j];
            }
        }
        __syncthreads();
    }
    #pragma unroll
    for (int i = 0; i < 4; ++i)
        #pragma unroll
        for (int j = 0; j < 3; ++j)
            out[(size_t)(m0 + ty * 4 + i) * NOUT + tx * 3 + j] = acc[i][j] + bgen[tx * 3 + j];
}

// ---------------------------------------------------------------------------
extern "C" void kernel_launch(void* const* d_in, const int* in_sizes, int n_in,
                              void* d_out, int out_size, void* d_ws, size_t ws_size,
                              hipStream_t stream) {
    const float* feats  = (const float*)d_in[0];
    // d_in[1] = text_length (all == NSTEPS), unused
    const float* Wi2h   = (const float*)d_in[2];
    const float* Wh2h   = (const float*)d_in[3];
    const float* bh2h   = (const float*)d_in[4];
    const float* Wscore = (const float*)d_in[5];
    const float* Wih    = (const float*)d_in[6];
    const float* Whh    = (const float*)d_in[7];
    const float* bih    = (const float*)d_in[8];
    const float* bhh    = (const float*)d_in[9];
    const float* Wgen   = (const float*)d_in[10];
    const float* bgen   = (const float*)d_in[11];
    float* out = (float*)d_out;

    // Workspace layout (floats).
    float* ws  = (float*)d_ws;
    float* fp  = ws;                      // 32768*512   = 16777216
    float* hid = fp + 16777216;           // 33*128*512  = 2162688 (slot 0 = h0 zeros)
    float* ctx = hid + 2162688;           // 65536

    hipMemsetAsync(hid, 0, 65536 * sizeof(float), stream);   // h0 = 0
    k_fp_gemm<<<1024, 256, 0, stream>>>(feats, Wi2h, fp);

    for (int s = 0; s < NSTEPS; ++s) {
        const float* h = hid + (size_t)s * 65536;
        float* hn      = hid + (size_t)(s + 1) * 65536;
        k_att<<<128, 1024, 0, stream>>>(fp, feats, h, Wh2h, bh2h, Wscore, ctx);
        k_gru<<<128, 256, 0, stream>>>(ctx, h, Wih, Whh, bih, bhh, hn);
    }
    k_gen<<<128, 256, 0, stream>>>(hid, Wgen, bgen, out);
}

// Round 3
// 2130.613 us; speedup vs baseline: 1.7237x; 1.7237x over previous
//
#include <hip/hip_runtime.h>
#include <math.h>

#define NBATCH 128
#define NTIME  256
#define NCH    512
#define NH     512
#define NSTEPS 32
#define NOUT   96
#define MTOT   32768

__device__ __forceinline__ float fast_tanh(float x) {
    x = fminf(fmaxf(x, -30.f), 30.f);
    float u = __expf(2.f * x);
    return (u - 1.f) / (u + 1.f);
}
__device__ __forceinline__ float fast_sigmoid(float x) {
    x = fminf(fmaxf(x, -30.f), 30.f);
    return 1.f / (1.f + __expf(-x));
}
__device__ __forceinline__ float wave_reduce_sum(float s) {
    #pragma unroll
    for (int off = 32; off; off >>= 1) s += __shfl_xor(s, off, 64);
    return s;
}
__device__ __forceinline__ float wave_reduce_max(float s) {
    #pragma unroll
    for (int off = 32; off; off >>= 1) s = fmaxf(s, __shfl_xor(s, off, 64));
    return s;
}

// ---------------------------------------------------------------------------
// feats_proj GEMM (unchanged; 217us, fix in a later round)
__global__ __launch_bounds__(256) void k_fp_gemm(const float* __restrict__ feats,
                                                 const float* __restrict__ Wi2h,
                                                 float* __restrict__ fp) {
    __shared__ float As[16][128];
    __shared__ float Bs[16][132];
    const int m0 = (blockIdx.x & 255) * 128;
    const int n0 = (blockIdx.x >> 8) * 128;
    const int tid = threadIdx.x;
    const int tx = tid & 15, ty = tid >> 4;
    float acc[8][8] = {};
    for (int k0 = 0; k0 < NCH; k0 += 16) {
        #pragma unroll
        for (int i = 0; i < 2; ++i) {
            int f4 = tid + i * 256;
            int kk = f4 >> 5, mm4 = (f4 & 31) << 2;
            *(float4*)(&As[kk][mm4]) =
                *(const float4*)(feats + (size_t)(k0 + kk) * MTOT + m0 + mm4);
        }
        #pragma unroll
        for (int i = 0; i < 2; ++i) {
            int f4 = tid + i * 256;
            int nn = f4 >> 2, kq = (f4 & 3) << 2;
            float4 v = *(const float4*)(Wi2h + (size_t)(n0 + nn) * NCH + k0 + kq);
            Bs[kq + 0][nn] = v.x; Bs[kq + 1][nn] = v.y;
            Bs[kq + 2][nn] = v.z; Bs[kq + 3][nn] = v.w;
        }
        __syncthreads();
        #pragma unroll
        for (int kk = 0; kk < 16; ++kk) {
            float a[8], b[8];
            *(float4*)(a)     = *(const float4*)(&As[kk][ty * 8]);
            *(float4*)(a + 4) = *(const float4*)(&As[kk][ty * 8 + 4]);
            *(float4*)(b)     = *(const float4*)(&Bs[kk][tx * 8]);
            *(float4*)(b + 4) = *(const float4*)(&Bs[kk][tx * 8 + 4]);
            #pragma unroll
            for (int i = 0; i < 8; ++i)
                #pragma unroll
                for (int j = 0; j < 8; ++j) acc[i][j] += a[i] * b[j];
        }
        __syncthreads();
    }
    #pragma unroll
    for (int i = 0; i < 8; ++i) {
        float* dst = fp + (size_t)(m0 + ty * 8 + i) * NH + n0 + tx * 8;
        *(float4*)(dst)     = *(float4*)(&acc[i][0]);
        *(float4*)(dst + 4) = *(float4*)(&acc[i][4]);
    }
}

// ---------------------------------------------------------------------------
// Transpose Wh2h[512][512] -> WT[k][j]  (one-time)
__global__ __launch_bounds__(256) void k_wt(const float* __restrict__ W,
                                            float* __restrict__ WT) {
    __shared__ float tl[32][33];
    const int bi = blockIdx.x & 15, bj = blockIdx.x >> 4;   // bi: k-tile, bj: j-tile
    const int tx = threadIdx.x & 31, ty8 = threadIdx.x >> 5;
    #pragma unroll
    for (int i = 0; i < 4; ++i) {
        int r = ty8 * 4 + i;
        tl[r][tx] = W[(size_t)(bj * 32 + r) * NH + bi * 32 + tx];
    }
    __syncthreads();
    #pragma unroll
    for (int i = 0; i < 4; ++i) {
        int c = ty8 * 4 + i;
        WT[(size_t)(bi * 32 + c) * NH + bj * 32 + tx] = tl[tx][c];
    }
}

// ---------------------------------------------------------------------------
// hp init for step 0 (h0 = 0): hp[b][j] = bh2h[j]
__global__ __launch_bounds__(1024) void k_hp0(const float* __restrict__ bh2h,
                                              float* __restrict__ hp) {
    int i = blockIdx.x * 1024 + threadIdx.x;    // 65536
    hp[i] = bh2h[i & 511];
}

// ---------------------------------------------------------------------------
// e[b][t] = sum_h tanh(fp[b][t][h] + hp[b][h]) * wscore[h]
// 256 blocks x 1024: block (b = blk>>1, t0 = (blk&1)*128); wave -> 8 t's.
__global__ __launch_bounds__(1024) void k_e(const float* __restrict__ fp,
                                            const float* __restrict__ hp,
                                            const float* __restrict__ wscore,
                                            float* __restrict__ e) {
    const int b = blockIdx.x >> 1;
    const int t0 = (blockIdx.x & 1) * 128;
    const int tid = threadIdx.x;
    const int lane = tid & 63, w = tid >> 6;
    float4 h0 = *(const float4*)(hp + (size_t)b * NH + lane * 8);
    float4 h1 = *(const float4*)(hp + (size_t)b * NH + lane * 8 + 4);
    float4 w0 = *(const float4*)(wscore + lane * 8);
    float4 w1 = *(const float4*)(wscore + lane * 8 + 4);
    #pragma unroll 2
    for (int it = 0; it < 8; ++it) {
        int t = t0 + w * 8 + it;
        const float4* p = (const float4*)(fp + (size_t)(b * NTIME + t) * NH + lane * 8);
        float4 v0 = p[0], v1 = p[1];
        float s = fast_tanh(v0.x + h0.x) * w0.x + fast_tanh(v0.y + h0.y) * w0.y +
                  fast_tanh(v0.z + h0.z) * w0.z + fast_tanh(v0.w + h0.w) * w0.w +
                  fast_tanh(v1.x + h1.x) * w1.x + fast_tanh(v1.y + h1.y) * w1.y +
                  fast_tanh(v1.z + h1.z) * w1.z + fast_tanh(v1.w + h1.w) * w1.w;
        s = wave_reduce_sum(s);
        if (lane == 0) e[b * NTIME + t] = s;
    }
}

// ---------------------------------------------------------------------------
// softmax(e[b]) + ctx[b][c] = sum_t feats[c][b][t]*alpha[t]
// 256 blocks x 1024: block (b = blk>>1, c0 = (blk&1)*256); wave -> 16 c's.
__global__ __launch_bounds__(1024) void k_ctx2(const float* __restrict__ e,
                                               const float* __restrict__ feats,
                                               float* __restrict__ ctx) {
    __shared__ float als[256];
    __shared__ float red[16];
    const int b = blockIdx.x >> 1;
    const int c0 = (blockIdx.x & 1) * 256;
    const int tid = threadIdx.x;
    const int lane = tid & 63, w = tid >> 6;
    float v = 0.f;
    if (tid < 256) v = e[b * NTIME + tid];
    float m = wave_reduce_max(v);
    if (lane == 0) red[w] = m;
    __syncthreads();
    m = fmaxf(fmaxf(red[0], red[1]), fmaxf(red[2], red[3]));
    float ex = (tid < 256) ? __expf(v - m) : 0.f;
    float s = wave_reduce_sum(ex);
    __syncthreads();
    if (lane == 0) red[w] = s;
    __syncthreads();
    s = red[0] + red[1] + red[2] + red[3];
    if (tid < 256) als[tid] = ex / s;
    __syncthreads();

    float4 al = *(const float4*)&als[lane * 4];
    #pragma unroll 4
    for (int cc = 0; cc < 16; ++cc) {
        int c = c0 + w * 16 + cc;
        float4 f = *(const float4*)(feats + (size_t)(c * NBATCH + b) * NTIME + lane * 4);
        float sc = f.x * al.x + f.y * al.y + f.z * al.z + f.w * al.w;
        sc = wave_reduce_sum(sc);
        if (lane == 0) ctx[(size_t)b * NCH + c] = sc;
    }
}

// ---------------------------------------------------------------------------
// Gates GEMM: g2[g][j][b] = sum_k A[b][k] * W[(g%3)*512+j][k]   (no bias)
// A = ctx for g<3, h for g>=3. 192 blocks x 1024.
// block: g = blk>>5, j0 = (blk&31)*16. thread: m2 = t&63; q=t>>6: nq=q&3,kq=q>>2.
// Thread-tile 2m x 4n, k-split 4 (kq), A in LDS transposed, W via s_load.
__global__ __launch_bounds__(1024) void k_gates(const float* __restrict__ ctx,
                                                const float* __restrict__ h,
                                                const float* __restrict__ Wih,
                                                const float* __restrict__ Whh,
                                                float* __restrict__ g2) {
    __shared__ float S[16384 + 8192];   // A_ldsT[128][128] + scr[4][16][128]
    float* A_ldsT = S;
    float* scr    = S + 16384;
    const int blk = blockIdx.x;
    const int g   = blk >> 5;
    const int j0  = (blk & 31) * 16;
    const float* A = (g < 3) ? ctx : h;
    const float* W = (g < 3) ? Wih : Whh;
    const int tid = threadIdx.x;
    const int m2  = tid & 63;
    const int q   = __builtin_amdgcn_readfirstlane(tid >> 6);
    const int nq  = q & 3, kq = q >> 2;
    const float* Wr0 = W + (size_t)((g % 3) * 512 + j0 + nq * 4 + 0) * NH;
    const float* Wr1 = W + (size_t)((g % 3) * 512 + j0 + nq * 4 + 1) * NH;
    const float* Wr2 = W + (size_t)((g % 3) * 512 + j0 + nq * 4 + 2) * NH;
    const float* Wr3 = W + (size_t)((g % 3) * 512 + j0 + nq * 4 + 3) * NH;
    float acc[2][4] = {};
    for (int kt = 0; kt < 4; ++kt) {
        // stage A[m][kt*128..+127] transposed -> A_ldsT[k][m]
        {
            int m = tid & 127, kc = tid >> 7;   // kc: 8 chunks of 16 k
            #pragma unroll
            for (int q4 = 0; q4 < 4; ++q4) {
                int kk = kc * 16 + q4 * 4;
                float4 vv = *(const float4*)(A + (size_t)m * NH + kt * 128 + kk);
                A_ldsT[(kk + 0) * 128 + m] = vv.x;
                A_ldsT[(kk + 1) * 128 + m] = vv.y;
                A_ldsT[(kk + 2) * 128 + m] = vv.z;
                A_ldsT[(kk + 3) * 128 + m] = vv.w;
            }
        }
        __syncthreads();
        const int kbase = kt * 128;
        #pragma unroll 8
        for (int kk = kq * 32; kk < kq * 32 + 32; ++kk) {
            float a0 = A_ldsT[kk * 128 + m2];
            float a1 = A_ldsT[kk * 128 + m2 + 64];
            float w0 = Wr0[kbase + kk], w1 = Wr1[kbase + kk];
            float w2 = Wr2[kbase + kk], w3 = Wr3[kbase + kk];
            acc[0][0] += a0 * w0; acc[0][1] += a0 * w1;
            acc[0][2] += a0 * w2; acc[0][3] += a0 * w3;
            acc[1][0] += a1 * w0; acc[1][1] += a1 * w1;
            acc[1][2] += a1 * w2; acc[1][3] += a1 * w3;
        }
        __syncthreads();
    }
    // write partials: scr[kq][nq*4+r][m]
    #pragma unroll
    for (int hi = 0; hi < 2; ++hi)
        #pragma unroll
        for (int r = 0; r < 4; ++r)
            scr[(kq * 16 + nq * 4 + r) * 128 + m2 + 64 * hi] = acc[hi][r];
    __syncthreads();
    // reduce 4 kq-partials, write g2[g][j0+nl][m]
    #pragma unroll
    for (int rep = 0; rep < 2; ++rep) {
        int oid = tid + rep * 1024;
        int m = oid & 127, nl = oid >> 7;
        float vv = scr[(0 * 16 + nl) * 128 + m] + scr[(1 * 16 + nl) * 128 + m] +
                   scr[(2 * 16 + nl) * 128 + m] + scr[(3 * 16 + nl) * 128 + m];
        g2[(size_t)(g * 512 + j0 + nl) * NBATCH + m] = vv;
    }
}

// ---------------------------------------------------------------------------
// Fused GRU-combine + next hp.
// 256 blocks x 1024: block (bq = blk>>3 -> 4 b's, jc = blk&7 -> 64 j's).
// combine: h_new from g2 (+biases) -> LDS h_s (+ write hid[s+1] if jc==0)
// hp[b][j] = h_new[b] . Wh2h[j] + bh2h[j]  via WT (coalesced) + LDS broadcast.
__global__ __launch_bounds__(1024) void k_comb_hp(const float* __restrict__ g2,
                                                  const float* __restrict__ hprev,
                                                  float* __restrict__ hidn,
                                                  const float* __restrict__ bih,
                                                  const float* __restrict__ bhh,
                                                  const float* __restrict__ WT,
                                                  const float* __restrict__ bh2h,
                                                  float* __restrict__ hp) {
    __shared__ float h_s[4 * 512];
    __shared__ float scr2[16 * 4 * 16 * 4];   // [kq][bi][jq] float4
    const int blk = blockIdx.x;
    const int b0 = (blk >> 3) * 4;
    const int jbase = (blk & 7) * 64;
    const int tid = threadIdx.x;
    // --- combine ---
    #pragma unroll
    for (int rep = 0; rep < 2; ++rep) {
        int idx = tid + rep * 1024;            // [0,2048)
        int bi = idx & 3, kk = idx >> 2;       // kk in [0,512)
        int b = b0 + bi;
        float ir = g2[(size_t)(0 * 512 + kk) * NBATCH + b] + bih[kk];
        float iz = g2[(size_t)(1 * 512 + kk) * NBATCH + b] + bih[512 + kk];
        float in_ = g2[(size_t)(2 * 512 + kk) * NBATCH + b] + bih[1024 + kk];
        float hr = g2[(size_t)(3 * 512 + kk) * NBATCH + b] + bhh[kk];
        float hz = g2[(size_t)(4 * 512 + kk) * NBATCH + b] + bhh[512 + kk];
        float hn = g2[(size_t)(5 * 512 + kk) * NBATCH + b] + bhh[1024 + kk];
        float r = fast_sigmoid(ir + hr);
        float z = fast_sigmoid(iz + hz);
        float ng = fast_tanh(in_ + r * hn);
        float hv = hprev[(size_t)b * NH + kk];
        float hnew = (1.f - z) * ng + z * hv;
        h_s[bi * 512 + kk] = hnew;
        if ((blk & 7) == 0) hidn[(size_t)b * NH + kk] = hnew;
    }
    __syncthreads();
    // --- hp GEMV ---
    {
        const int jq = tid & 15, bi = (tid >> 4) & 3, kq = tid >> 6;  // kq in [0,16)
        const int j = jbase + jq * 4;
        float4 acc = make_float4(0.f, 0.f, 0.f, 0.f);
        #pragma unroll 8
        for (int kk = 0; kk < 32; ++kk) {
            int k = kq * 32 + kk;
            float4 wv = *(const float4*)(WT + (size_t)k * NH + j);
            float hv = h_s[bi * 512 + k];
            acc.x += hv * wv.x; acc.y += hv * wv.y;
            acc.z += hv * wv.z; acc.w += hv * wv.w;
        }
        *(float4*)&scr2[((kq * 4 + bi) * 16 + jq) * 4] = acc;
    }
    __syncthreads();
    if (tid < 64) {
        const int bi = tid >> 4, jq = tid & 15;
        float4 sum = make_float4(0.f, 0.f, 0.f, 0.f);
        #pragma unroll
        for (int kq = 0; kq < 16; ++kq) {
            float4 p = *(const float4*)&scr2[((kq * 4 + bi) * 16 + jq) * 4];
            sum.x += p.x; sum.y += p.y; sum.z += p.z; sum.w += p.w;
        }
        int j = jbase + jq * 4;
        float4 bb = *(const float4*)(bh2h + j);
        sum.x += bb.x; sum.y += bb.y; sum.z += bb.z; sum.w += bb.w;
        *(float4*)(hp + (size_t)(b0 + bi) * NH + j) = sum;
    }
}

// ---------------------------------------------------------------------------
// generator GEMM (unchanged)
__global__ __launch_bounds__(256) void k_gen(const float* __restrict__ hid,
                                             const float* __restrict__ Wgen,
                                             const float* __restrict__ bgen,
                                             float* __restrict__ out) {
    __shared__ float As[32][36];
    __shared__ float Bs[32][97];
    const int m0 = blockIdx.x * 32;
    const int tid = threadIdx.x;
    const int tx = tid & 31, ty = tid >> 5;
    float acc[4][3] = {};
    for (int k0 = 0; k0 < 512; k0 += 32) {
        {
            int mm = tid >> 3, kq = (tid & 7) << 2;
            int m = m0 + mm, s = m & 31, b = m >> 5;
            float4 v = *(const float4*)(hid + (size_t)(s + 1) * 65536 + b * 512 + k0 + kq);
            *(float4*)(&As[mm][kq]) = v;
        }
        #pragma unroll
        for (int i = 0; i < 3; ++i) {
            int f4 = tid + i * 256;
            int nn = f4 >> 3, kq = (f4 & 7) << 2;
            float4 v = *(const float4*)(Wgen + (size_t)nn * 512 + k0 + kq);
            Bs[kq + 0][nn] = v.x; Bs[kq + 1][nn] = v.y;
            Bs[kq + 2][nn] = v.z; Bs[kq + 3][nn] = v.w;
        }
        __syncthreads();
        #pragma unroll
        for (int kk = 0; kk < 32; ++kk) {
            float bv[3];
            #pragma unroll
            for (int j = 0; j < 3; ++j) bv[j] = Bs[kk][tx * 3 + j];
            #pragma unroll
            for (int i = 0; i < 4; ++i) {
                float a = As[ty * 4 + i][kk];
                #pragma unroll
                for (int j = 0; j < 3; ++j) acc[i][j] += a * bv[j];
            }
        }
        __syncthreads();
    }
    #pragma unroll
    for (int i = 0; i < 4; ++i)
        #pragma unroll
        for (int j = 0; j < 3; ++j)
            out[(size_t)(m0 + ty * 4 + i) * NOUT + tx * 3 + j] = acc[i][j] + bgen[tx * 3 + j];
}

// ---------------------------------------------------------------------------
extern "C" void kernel_launch(void* const* d_in, const int* in_sizes, int n_in,
                              void* d_out, int out_size, void* d_ws, size_t ws_size,
                              hipStream_t stream) {
    const float* feats  = (const float*)d_in[0];
    const float* Wi2h   = (const float*)d_in[2];
    const float* Wh2h   = (const float*)d_in[3];
    const float* bh2h   = (const float*)d_in[4];
    const float* Wscore = (const float*)d_in[5];
    const float* Wih    = (const float*)d_in[6];
    const float* Whh    = (const float*)d_in[7];
    const float* bih    = (const float*)d_in[8];
    const float* bhh    = (const float*)d_in[9];
    const float* Wgen   = (const float*)d_in[10];
    const float* bgen   = (const float*)d_in[11];
    float* out = (float*)d_out;

    // ws: fp | hid(33 slots) | WT | hpctx      total 77.07 MB
    float* ws  = (float*)d_ws;
    float* fp    = ws;                    // 16777216
    float* hid   = fp + 16777216;         // 2162688
    float* WT    = hid + 2162688;         // 262144
    float* hpctx = WT + 262144;           // 65536  (hp and ctx alias, disjoint lifetimes)
    // e and g2 live in d_out (fully overwritten by k_gen at the end)
    float* e  = out;                      // 32768  (aliases g2 head; disjoint lifetimes)
    float* g2 = out;                      // 6*512*128 = 393216 = out_size

    hipMemsetAsync(hid, 0, 65536 * sizeof(float), stream);   // h0 = 0
    k_wt<<<256, 256, 0, stream>>>(Wh2h, WT);
    k_fp_gemm<<<1024, 256, 0, stream>>>(feats, Wi2h, fp);
    k_hp0<<<64, 1024, 0, stream>>>(bh2h, hpctx);

    for (int s = 0; s < NSTEPS; ++s) {
        const float* h = hid + (size_t)s * 65536;
        float* hn      = hid + (size_t)(s + 1) * 65536;
        k_e<<<256, 1024, 0, stream>>>(fp, hpctx, Wscore, e);
        k_ctx2<<<256, 1024, 0, stream>>>(e, feats, hpctx);          // writes ctx (hp dead)
        k_gates<<<192, 1024, 0, stream>>>(hpctx, h, Wih, Whh, g2);  // reads ctx
        k_comb_hp<<<256, 1024, 0, stream>>>(g2, h, hn, bih, bhh, WT, bh2h, hpctx); // writes hp
    }
    k_gen<<<128, 256, 0, stream>>>(hid, Wgen, bgen, out);
}

// Round 4
// 1851.950 us; speedup vs baseline: 1.9831x; 1.1505x over previous
//
#include <hip/hip_runtime.h>
#include <math.h>

#define NBATCH 128
#define NTIME  256
#define NCH    512
#define NH     512
#define NSTEPS 32
#define NOUT   96
#define MTOT   32768

typedef __attribute__((ext_vector_type(8))) short short8v;
typedef __attribute__((ext_vector_type(4))) float f32x4;

__device__ __forceinline__ float fast_tanh(float x) {
    x = fminf(fmaxf(x, -30.f), 30.f);
    float u = __expf(2.f * x);
    return (u - 1.f) / (u + 1.f);
}
__device__ __forceinline__ float fast_sigmoid(float x) {
    x = fminf(fmaxf(x, -30.f), 30.f);
    return 1.f / (1.f + __expf(-x));
}
__device__ __forceinline__ float wave_reduce_sum(float s) {
    #pragma unroll
    for (int off = 32; off; off >>= 1) s += __shfl_xor(s, off, 64);
    return s;
}
__device__ __forceinline__ float wave_reduce_max(float s) {
    #pragma unroll
    for (int off = 32; off; off >>= 1) s = fmaxf(s, __shfl_xor(s, off, 64));
    return s;
}
__device__ __forceinline__ unsigned short f2bf(float f) {
    unsigned u = __builtin_bit_cast(unsigned, f);
    return (unsigned short)((u + 0x7FFFu + ((u >> 16) & 1u)) >> 16);
}

// ---------------------------------------------------------------------------
// FALLBACK fp32 GEMM (round-3 version; used only if ws too small for bf16 path)
__global__ __launch_bounds__(256) void k_fp_gemm(const float* __restrict__ feats,
                                                 const float* __restrict__ Wi2h,
                                                 float* __restrict__ fp) {
    __shared__ float As[16][128];
    __shared__ float Bs[16][132];
    const int m0 = (blockIdx.x & 255) * 128;
    const int n0 = (blockIdx.x >> 8) * 128;
    const int tid = threadIdx.x;
    const int tx = tid & 15, ty = tid >> 4;
    float acc[8][8] = {};
    for (int k0 = 0; k0 < NCH; k0 += 16) {
        #pragma unroll
        for (int i = 0; i < 2; ++i) {
            int f4 = tid + i * 256;
            int kk = f4 >> 5, mm4 = (f4 & 31) << 2;
            *(float4*)(&As[kk][mm4]) =
                *(const float4*)(feats + (size_t)(k0 + kk) * MTOT + m0 + mm4);
        }
        #pragma unroll
        for (int i = 0; i < 2; ++i) {
            int f4 = tid + i * 256;
            int nn = f4 >> 2, kq = (f4 & 3) << 2;
            float4 v = *(const float4*)(Wi2h + (size_t)(n0 + nn) * NCH + k0 + kq);
            Bs[kq + 0][nn] = v.x; Bs[kq + 1][nn] = v.y;
            Bs[kq + 2][nn] = v.z; Bs[kq + 3][nn] = v.w;
        }
        __syncthreads();
        #pragma unroll
        for (int kk = 0; kk < 16; ++kk) {
            float a[8], b[8];
            *(float4*)(a)     = *(const float4*)(&As[kk][ty * 8]);
            *(float4*)(a + 4) = *(const float4*)(&As[kk][ty * 8 + 4]);
            *(float4*)(b)     = *(const float4*)(&Bs[kk][tx * 8]);
            *(float4*)(b + 4) = *(const float4*)(&Bs[kk][tx * 8 + 4]);
            #pragma unroll
            for (int i = 0; i < 8; ++i)
                #pragma unroll
                for (int j = 0; j < 8; ++j) acc[i][j] += a[i] * b[j];
        }
        __syncthreads();
    }
    #pragma unroll
    for (int i = 0; i < 8; ++i) {
        float* dst = fp + (size_t)(m0 + ty * 8 + i) * NH + n0 + tx * 8;
        *(float4*)(dst)     = *(float4*)(&acc[i][0]);
        *(float4*)(dst + 4) = *(float4*)(&acc[i][4]);
    }
}

// ---------------------------------------------------------------------------
// Wi2h fp32 [512][512] -> bf16 same layout
__global__ __launch_bounds__(256) void k_w2bf(const float* __restrict__ W,
                                              unsigned short* __restrict__ Wb) {
    #pragma unroll
    for (int r = 0; r < 4; ++r) {
        int idx = (blockIdx.x * 256 + threadIdx.x) + r * 16384;   // float4 index
        float4 v = *(const float4*)(W + (size_t)idx * 4);
        ushort4 o;
        o.x = f2bf(v.x); o.y = f2bf(v.y); o.z = f2bf(v.z); o.w = f2bf(v.w);
        *(ushort4*)(Wb + (size_t)idx * 4) = o;
    }
}

// ---------------------------------------------------------------------------
// feats fp32 [k=512][m=32768] -> featsT bf16 [m][k]   (64x64 tiles via LDS)
__global__ __launch_bounds__(256) void k_feats2bf(const float* __restrict__ feats,
                                                  unsigned short* __restrict__ Fb) {
    __shared__ float tl[64][65];
    const int m0 = (blockIdx.x & 511) * 64;
    const int k0 = (blockIdx.x >> 9) * 64;
    const int tid = threadIdx.x;
    #pragma unroll
    for (int p = 0; p < 4; ++p) {
        int fid = tid + p * 256;                 // 1024 float4
        int row = fid >> 4, c4 = fid & 15;
        float4 v = *(const float4*)(feats + (size_t)(k0 + row) * MTOT + m0 + c4 * 4);
        tl[row][c4 * 4 + 0] = v.x; tl[row][c4 * 4 + 1] = v.y;
        tl[row][c4 * 4 + 2] = v.z; tl[row][c4 * 4 + 3] = v.w;
    }
    __syncthreads();
    #pragma unroll
    for (int p = 0; p < 4; ++p) {
        int cid = tid + p * 256;                 // 1024 chunks of 4 bf16
        int mm = cid >> 4, ch = cid & 15;
        ushort4 o;
        o.x = f2bf(tl[ch * 4 + 0][mm]);
        o.y = f2bf(tl[ch * 4 + 1][mm]);
        o.z = f2bf(tl[ch * 4 + 2][mm]);
        o.w = f2bf(tl[ch * 4 + 3][mm]);
        *(ushort4*)(Fb + (size_t)(m0 + mm) * 512 + k0 + ch * 4) = o;
    }
}

// ---------------------------------------------------------------------------
// MFMA GEMM: fp[m][h] = sum_k featsT[m][k] * Wi2h[h][k]  (bf16 in, fp32 out)
// D-fragments: M-dim = h, N-dim = m. Block: 128h x 256m, 4 waves (2x2),
// each wave 64h x 128m = 4x8 fragments of 16x16. BK=64, XOR-swizzled LDS.
__global__ __launch_bounds__(256) void k_fp_mfma(const unsigned short* __restrict__ Wb,
                                                 const unsigned short* __restrict__ Fb,
                                                 float* __restrict__ fp) {
    __shared__ unsigned short As[128 * 64];   // 16KB: rows h, 64 k (8 chunks of 16B)
    __shared__ unsigned short Bs[256 * 64];   // 32KB: rows m
    const int m0 = (blockIdx.x & 127) * 256;
    const int h0 = (blockIdx.x >> 7) * 128;
    const int tid = threadIdx.x;
    const int lane = tid & 63, wid = tid >> 6;
    const int wh = wid & 1, wm = wid >> 1;
    f32x4 acc[4][8];
    #pragma unroll
    for (int i = 0; i < 4; ++i)
        #pragma unroll
        for (int j = 0; j < 8; ++j) acc[i][j] = (f32x4)0.f;

    for (int k0 = 0; k0 < 512; k0 += 64) {
        #pragma unroll
        for (int i = 0; i < 4; ++i) {        // A: 1024 chunks
            int cid = tid + i * 256;
            int row = cid >> 3, ch = cid & 7;
            uint4 v = *(const uint4*)(Wb + (size_t)(h0 + row) * 512 + k0 + ch * 8);
            *(uint4*)(As + row * 64 + ((ch ^ (row & 7)) << 3)) = v;
        }
        #pragma unroll
        for (int i = 0; i < 8; ++i) {        // B: 2048 chunks
            int cid = tid + i * 256;
            int row = cid >> 3, ch = cid & 7;
            uint4 v = *(const uint4*)(Fb + (size_t)(m0 + row) * 512 + k0 + ch * 8);
            *(uint4*)(Bs + row * 64 + ((ch ^ (row & 7)) << 3)) = v;
        }
        __syncthreads();
        #pragma unroll
        for (int ks = 0; ks < 2; ++ks) {
            short8v a[4], b[8];
            #pragma unroll
            for (int hf = 0; hf < 4; ++hf) {
                int row = wh * 64 + hf * 16 + (lane & 15);
                int ch = ks * 4 + (lane >> 4);
                a[hf] = *(const short8v*)(As + row * 64 + ((ch ^ (row & 7)) << 3));
            }
            #pragma unroll
            for (int mf = 0; mf < 8; ++mf) {
                int row = wm * 128 + mf * 16 + (lane & 15);
                int ch = ks * 4 + (lane >> 4);
                b[mf] = *(const short8v*)(Bs + row * 64 + ((ch ^ (row & 7)) << 3));
            }
            #pragma unroll
            for (int hf = 0; hf < 4; ++hf)
                #pragma unroll
                for (int mf = 0; mf < 8; ++mf)
                    acc[hf][mf] = __builtin_amdgcn_mfma_f32_16x16x32_bf16(
                        a[hf], b[mf], acc[hf][mf], 0, 0, 0);
        }
        __syncthreads();
    }
    #pragma unroll
    for (int hf = 0; hf < 4; ++hf) {
        int h = h0 + wh * 64 + hf * 16 + (lane >> 4) * 4;
        #pragma unroll
        for (int mf = 0; mf < 8; ++mf) {
            int m = m0 + wm * 128 + mf * 16 + (lane & 15);
            *(f32x4*)(fp + (size_t)m * 512 + h) = acc[hf][mf];
        }
    }
}

// ---------------------------------------------------------------------------
// Transpose Wh2h[512][512] -> WT[k][j]  (one-time)
__global__ __launch_bounds__(256) void k_wt(const float* __restrict__ W,
                                            float* __restrict__ WT) {
    __shared__ float tl[32][33];
    const int bi = blockIdx.x & 15, bj = blockIdx.x >> 4;
    const int tx = threadIdx.x & 31, ty8 = threadIdx.x >> 5;
    #pragma unroll
    for (int i = 0; i < 4; ++i) {
        int r = ty8 * 4 + i;
        tl[r][tx] = W[(size_t)(bj * 32 + r) * NH + bi * 32 + tx];
    }
    __syncthreads();
    #pragma unroll
    for (int i = 0; i < 4; ++i) {
        int c = ty8 * 4 + i;
        WT[(size_t)(bi * 32 + c) * NH + bj * 32 + tx] = tl[tx][c];
    }
}

// ---------------------------------------------------------------------------
__global__ __launch_bounds__(1024) void k_hp0(const float* __restrict__ bh2h,
                                              float* __restrict__ hp) {
    int i = blockIdx.x * 1024 + threadIdx.x;
    hp[i] = bh2h[i & 511];
}

// ---------------------------------------------------------------------------
// e[b][t] = sum_h tanh(fp[b][t][h] + hp[b][h]) * wscore[h]
// 512 blocks x 512: b = blk>>2, t0 = (blk&3)*64; wave (8/block) -> 8 t's.
__global__ __launch_bounds__(512) void k_e(const float* __restrict__ fp,
                                           const float* __restrict__ hp,
                                           const float* __restrict__ wscore,
                                           float* __restrict__ e) {
    const int b = blockIdx.x >> 2;
    const int t0 = (blockIdx.x & 3) * 64;
    const int tid = threadIdx.x;
    const int lane = tid & 63, w = tid >> 6;
    float4 h0 = *(const float4*)(hp + (size_t)b * NH + lane * 8);
    float4 h1 = *(const float4*)(hp + (size_t)b * NH + lane * 8 + 4);
    float4 w0 = *(const float4*)(wscore + lane * 8);
    float4 w1 = *(const float4*)(wscore + lane * 8 + 4);
    #pragma unroll 2
    for (int it = 0; it < 8; ++it) {
        int t = t0 + w * 8 + it;
        const float4* p = (const float4*)(fp + (size_t)(b * NTIME + t) * NH + lane * 8);
        float4 v0 = p[0], v1 = p[1];
        float s = fast_tanh(v0.x + h0.x) * w0.x + fast_tanh(v0.y + h0.y) * w0.y +
                  fast_tanh(v0.z + h0.z) * w0.z + fast_tanh(v0.w + h0.w) * w0.w +
                  fast_tanh(v1.x + h1.x) * w1.x + fast_tanh(v1.y + h1.y) * w1.y +
                  fast_tanh(v1.z + h1.z) * w1.z + fast_tanh(v1.w + h1.w) * w1.w;
        s = wave_reduce_sum(s);
        if (lane == 0) e[b * NTIME + t] = s;
    }
}

// ---------------------------------------------------------------------------
// softmax(e[b]) + ctx[b][c] = sum_t feats[c][b][t]*alpha[t]
// 512 blocks x 512: b = blk>>2, c0 = (blk&3)*128; wave -> 16 c's.
__global__ __launch_bounds__(512) void k_ctx2(const float* __restrict__ e,
                                              const float* __restrict__ feats,
                                              float* __restrict__ ctx) {
    __shared__ float als[256];
    __shared__ float red[8];
    const int b = blockIdx.x >> 2;
    const int c0 = (blockIdx.x & 3) * 128;
    const int tid = threadIdx.x;
    const int lane = tid & 63, w = tid >> 6;
    float v = (tid < 256) ? e[b * NTIME + tid] : -3.4e38f;
    float m = wave_reduce_max(v);
    if (lane == 0) red[w] = m;
    __syncthreads();
    m = red[0];
    #pragma unroll
    for (int i = 1; i < 8; ++i) m = fmaxf(m, red[i]);
    float ex = (tid < 256) ? __expf(v - m) : 0.f;
    float s = wave_reduce_sum(ex);
    __syncthreads();
    if (lane == 0) red[w] = s;
    __syncthreads();
    s = 0.f;
    #pragma unroll
    for (int i = 0; i < 8; ++i) s += red[i];
    if (tid < 256) als[tid] = ex / s;
    __syncthreads();

    float4 al = *(const float4*)&als[lane * 4];
    #pragma unroll 4
    for (int cc = 0; cc < 16; ++cc) {
        int c = c0 + w * 16 + cc;
        float4 f = *(const float4*)(feats + (size_t)(c * NBATCH + b) * NTIME + lane * 4);
        float sc = f.x * al.x + f.y * al.y + f.z * al.z + f.w * al.w;
        sc = wave_reduce_sum(sc);
        if (lane == 0) ctx[(size_t)b * NCH + c] = sc;
    }
}

// ---------------------------------------------------------------------------
// Gates GEMM: g2[g][j][b] = sum_k A[b][k] * W[(g%3)*512+j][k]   (no bias)
__global__ __launch_bounds__(1024) void k_gates(const float* __restrict__ ctx,
                                                const float* __restrict__ h,
                                                const float* __restrict__ Wih,
                                                const float* __restrict__ Whh,
                                                float* __restrict__ g2) {
    __shared__ float S[16384 + 8192];
    float* A_ldsT = S;
    float* scr    = S + 16384;
    const int blk = blockIdx.x;
    const int g   = blk >> 5;
    const int j0  = (blk & 31) * 16;
    const float* A = (g < 3) ? ctx : h;
    const float* W = (g < 3) ? Wih : Whh;
    const int tid = threadIdx.x;
    const int m2  = tid & 63;
    const int q   = __builtin_amdgcn_readfirstlane(tid >> 6);
    const int nq  = q & 3, kq = q >> 2;
    const float* Wr0 = W + (size_t)((g % 3) * 512 + j0 + nq * 4 + 0) * NH;
    const float* Wr1 = W + (size_t)((g % 3) * 512 + j0 + nq * 4 + 1) * NH;
    const float* Wr2 = W + (size_t)((g % 3) * 512 + j0 + nq * 4 + 2) * NH;
    const float* Wr3 = W + (size_t)((g % 3) * 512 + j0 + nq * 4 + 3) * NH;
    float acc[2][4] = {};
    for (int kt = 0; kt < 4; ++kt) {
        {
            int m = tid & 127, kc = tid >> 7;
            #pragma unroll
            for (int q4 = 0; q4 < 4; ++q4) {
                int kk = kc * 16 + q4 * 4;
                float4 vv = *(const float4*)(A + (size_t)m * NH + kt * 128 + kk);
                A_ldsT[(kk + 0) * 128 + m] = vv.x;
                A_ldsT[(kk + 1) * 128 + m] = vv.y;
                A_ldsT[(kk + 2) * 128 + m] = vv.z;
                A_ldsT[(kk + 3) * 128 + m] = vv.w;
            }
        }
        __syncthreads();
        const int kbase = kt * 128;
        #pragma unroll 8
        for (int kk = kq * 32; kk < kq * 32 + 32; ++kk) {
            float a0 = A_ldsT[kk * 128 + m2];
            float a1 = A_ldsT[kk * 128 + m2 + 64];
            float w0 = Wr0[kbase + kk], w1 = Wr1[kbase + kk];
            float w2 = Wr2[kbase + kk], w3 = Wr3[kbase + kk];
            acc[0][0] += a0 * w0; acc[0][1] += a0 * w1;
            acc[0][2] += a0 * w2; acc[0][3] += a0 * w3;
            acc[1][0] += a1 * w0; acc[1][1] += a1 * w1;
            acc[1][2] += a1 * w2; acc[1][3] += a1 * w3;
        }
        __syncthreads();
    }
    #pragma unroll
    for (int hi = 0; hi < 2; ++hi)
        #pragma unroll
        for (int r = 0; r < 4; ++r)
            scr[(kq * 16 + nq * 4 + r) * 128 + m2 + 64 * hi] = acc[hi][r];
    __syncthreads();
    #pragma unroll
    for (int rep = 0; rep < 2; ++rep) {
        int oid = tid + rep * 1024;
        int m = oid & 127, nl = oid >> 7;
        float vv = scr[(0 * 16 + nl) * 128 + m] + scr[(1 * 16 + nl) * 128 + m] +
                   scr[(2 * 16 + nl) * 128 + m] + scr[(3 * 16 + nl) * 128 + m];
        g2[(size_t)(g * 512 + j0 + nl) * NBATCH + m] = vv;
    }
}

// ---------------------------------------------------------------------------
// Fused GRU-combine + next hp.
__global__ __launch_bounds__(1024) void k_comb_hp(const float* __restrict__ g2,
                                                  const float* __restrict__ hprev,
                                                  float* __restrict__ hidn,
                                                  const float* __restrict__ bih,
                                                  const float* __restrict__ bhh,
                                                  const float* __restrict__ WT,
                                                  const float* __restrict__ bh2h,
                                                  float* __restrict__ hp) {
    __shared__ float h_s[4 * 512];
    __shared__ float scr2[16 * 4 * 16 * 4];
    const int blk = blockIdx.x;
    const int b0 = (blk >> 3) * 4;
    const int jbase = (blk & 7) * 64;
    const int tid = threadIdx.x;
    #pragma unroll
    for (int rep = 0; rep < 2; ++rep) {
        int idx = tid + rep * 1024;
        int bi = idx & 3, kk = idx >> 2;
        int b = b0 + bi;
        float ir = g2[(size_t)(0 * 512 + kk) * NBATCH + b] + bih[kk];
        float iz = g2[(size_t)(1 * 512 + kk) * NBATCH + b] + bih[512 + kk];
        float in_ = g2[(size_t)(2 * 512 + kk) * NBATCH + b] + bih[1024 + kk];
        float hr = g2[(size_t)(3 * 512 + kk) * NBATCH + b] + bhh[kk];
        float hz = g2[(size_t)(4 * 512 + kk) * NBATCH + b] + bhh[512 + kk];
        float hn = g2[(size_t)(5 * 512 + kk) * NBATCH + b] + bhh[1024 + kk];
        float r = fast_sigmoid(ir + hr);
        float z = fast_sigmoid(iz + hz);
        float ng = fast_tanh(in_ + r * hn);
        float hv = hprev[(size_t)b * NH + kk];
        float hnew = (1.f - z) * ng + z * hv;
        h_s[bi * 512 + kk] = hnew;
        if ((blk & 7) == 0) hidn[(size_t)b * NH + kk] = hnew;
    }
    __syncthreads();
    {
        const int jq = tid & 15, bi = (tid >> 4) & 3, kq = tid >> 6;
        const int j = jbase + jq * 4;
        float4 acc = make_float4(0.f, 0.f, 0.f, 0.f);
        #pragma unroll 8
        for (int kk = 0; kk < 32; ++kk) {
            int k = kq * 32 + kk;
            float4 wv = *(const float4*)(WT + (size_t)k * NH + j);
            float hv = h_s[bi * 512 + k];
            acc.x += hv * wv.x; acc.y += hv * wv.y;
            acc.z += hv * wv.z; acc.w += hv * wv.w;
        }
        *(float4*)&scr2[((kq * 4 + bi) * 16 + jq) * 4] = acc;
    }
    __syncthreads();
    if (tid < 64) {
        const int bi = tid >> 4, jq = tid & 15;
        float4 sum = make_float4(0.f, 0.f, 0.f, 0.f);
        #pragma unroll
        for (int kq = 0; kq < 16; ++kq) {
            float4 p = *(const float4*)&scr2[((kq * 4 + bi) * 16 + jq) * 4];
            sum.x += p.x; sum.y += p.y; sum.z += p.z; sum.w += p.w;
        }
        int j = jbase + jq * 4;
        float4 bb = *(const float4*)(bh2h + j);
        sum.x += bb.x; sum.y += bb.y; sum.z += bb.z; sum.w += bb.w;
        *(float4*)(hp + (size_t)(b0 + bi) * NH + j) = sum;
    }
}

// ---------------------------------------------------------------------------
__global__ __launch_bounds__(256) void k_gen(const float* __restrict__ hid,
                                             const float* __restrict__ Wgen,
                                             const float* __restrict__ bgen,
                                             float* __restrict__ out) {
    __shared__ float As[32][36];
    __shared__ float Bs[32][97];
    const int m0 = blockIdx.x * 32;
    const int tid = threadIdx.x;
    const int tx = tid & 31, ty = tid >> 5;
    float acc[4][3] = {};
    for (int k0 = 0; k0 < 512; k0 += 32) {
        {
            int mm = tid >> 3, kq = (tid & 7) << 2;
            int m = m0 + mm, s = m & 31, b = m >> 5;
            float4 v = *(const float4*)(hid + (size_t)(s + 1) * 65536 + b * 512 + k0 + kq);
            *(float4*)(&As[mm][kq]) = v;
        }
        #pragma unroll
        for (int i = 0; i < 3; ++i) {
            int f4 = tid + i * 256;
            int nn = f4 >> 3, kq = (f4 & 7) << 2;
            float4 v = *(const float4*)(Wgen + (size_t)nn * 512 + k0 + kq);
            Bs[kq + 0][nn] = v.x; Bs[kq + 1][nn] = v.y;
            Bs[kq + 2][nn] = v.z; Bs[kq + 3][nn] = v.w;
        }
        __syncthreads();
        #pragma unroll
        for (int kk = 0; kk < 32; ++kk) {
            float bv[3];
            #pragma unroll
            for (int j = 0; j < 3; ++j) bv[j] = Bs[kk][tx * 3 + j];
            #pragma unroll
            for (int i = 0; i < 4; ++i) {
                float a = As[ty * 4 + i][kk];
                #pragma unroll
                for (int j = 0; j < 3; ++j) acc[i][j] += a * bv[j];
            }
        }
        __syncthreads();
    }
    #pragma unroll
    for (int i = 0; i < 4; ++i)
        #pragma unroll
        for (int j = 0; j < 3; ++j)
            out[(size_t)(m0 + ty * 4 + i) * NOUT + tx * 3 + j] = acc[i][j] + bgen[tx * 3 + j];
}

// ---------------------------------------------------------------------------
extern "C" void kernel_launch(void* const* d_in, const int* in_sizes, int n_in,
                              void* d_out, int out_size, void* d_ws, size_t ws_size,
                              hipStream_t stream) {
    const float* feats  = (const float*)d_in[0];
    const float* Wi2h   = (const float*)d_in[2];
    const float* Wh2h   = (const float*)d_in[3];
    const float* bh2h   = (const float*)d_in[4];
    const float* Wscore = (const float*)d_in[5];
    const float* Wih    = (const float*)d_in[6];
    const float* Whh    = (const float*)d_in[7];
    const float* bih    = (const float*)d_in[8];
    const float* bhh    = (const float*)d_in[9];
    const float* Wgen   = (const float*)d_in[10];
    const float* bgen   = (const float*)d_in[11];
    float* out = (float*)d_out;

    // ws layout (floats): fp(16777216) hid(2162688) WT(262144) hpctx(65536)
    //                     [W_b(131072) featsT_b(8388608) -- bf16 path only]
    float* ws  = (float*)d_ws;
    float* fp    = ws;
    float* hid   = fp + 16777216;
    float* WT    = hid + 2162688;
    float* hpctx = WT + 262144;
    unsigned short* W_b = (unsigned short*)(hpctx + 65536);
    unsigned short* Fb  = (unsigned short*)(hpctx + 65536 + 131072);
    const size_t need_big = (size_t)(16777216 + 2162688 + 262144 + 65536 + 131072 + 8388608) * 4;
    const bool big = ws_size >= need_big;

    float* e  = out;                      // aliases g2 head; disjoint lifetimes
    float* g2 = out;                      // 6*512*128 = 393216 = out_size

    hipMemsetAsync(hid, 0, 65536 * sizeof(float), stream);   // h0 = 0
    k_wt<<<256, 256, 0, stream>>>(Wh2h, WT);
    if (big) {
        k_w2bf<<<64, 256, 0, stream>>>(Wi2h, W_b);
        k_feats2bf<<<4096, 256, 0, stream>>>(feats, Fb);
        k_fp_mfma<<<512, 256, 0, stream>>>(W_b, Fb, fp);
    } else {
        k_fp_gemm<<<1024, 256, 0, stream>>>(feats, Wi2h, fp);
    }
    k_hp0<<<64, 1024, 0, stream>>>(bh2h, hpctx);

    for (int s = 0; s < NSTEPS; ++s) {
        const float* h = hid + (size_t)s * 65536;
        float* hn      = hid + (size_t)(s + 1) * 65536;
        k_e<<<512, 512, 0, stream>>>(fp, hpctx, Wscore, e);
        k_ctx2<<<512, 512, 0, stream>>>(e, feats, hpctx);
        k_gates<<<192, 1024, 0, stream>>>(hpctx, h, Wih, Whh, g2);
        k_comb_hp<<<256, 1024, 0, stream>>>(g2, h, hn, bih, bhh, WT, bh2h, hpctx);
    }
    k_gen<<<128, 256, 0, stream>>>(hid, Wgen, bgen, out);
}